// Round 1
// baseline (1773.760 us; speedup 1.0000x reference)
//
#include <hip/hip_runtime.h>
#include <cstddef>

// RelPositionMultiHeadAttention (Conformer / Transformer-XL style), fp32 baseline.
// B=4, T=1024, D=1024, H=8, DK=128, P=2*T-1=2047.
//
// Pipeline:
//   1. gemm_proj: q = query@Wq+bq  -> writes q_u=q+pos_bias_u, q_v=q+pos_bias_v  (mode 1)
//      gemm_proj: k = key@Wk+bk, v = value@Wv+bv, p = pos_emb@Wp (no bias)       (mode 0)
//   2. per b-chunk:
//      attn_scores: scores[t,s] = SCALE*qu[t]·k[s] + (mask? NEG_INF : SCALE*qv[t]·p[s+T-1-t])
//                   (rel_shift identity: shifted_bd[t,s] = bd[t, s+T-1-t])
//      softmax_rows: row softmax; all-masked row -> probs=0 (so out=bo, matches ref)
//      attn_pv: ctx[t, h*DK+n] = sum_s probs[t,s]*v[s, h*DK+n]
//   3. gemm_proj: out = ctx@Wo + bo
//
// Workspace layout (floats): qu | qv | k | v | ctx | p | scores(SB*H*T*T)
//   base = 5*4194304 + 2096128 = 23,067,648 floats = 92.3 MB; scores chunk 33.5 MB/batch.

#define B_ 4
#define T_ 1024
#define D_ 1024
#define H_ 8
#define DK_ 128
#define P_ 2047
#define SCALE_F 0.08838834764831845f
#define NEG_INF_F (-10000.0f)

__device__ __forceinline__ float dot4(float4 a, float4 b) {
    return a.x*b.x + a.y*b.y + a.z*b.z + a.w*b.w;
}

// ---------------------------------------------------------------------------
// C[M,1024] = A[M,1024] @ W[1024,1024] (+bias).
// tile 128x128, BK=16, 256 threads, per-thread 8x8 (2x2 blocks of 4x4).
// mode 0: out0 = r (+bias)
// mode 1: out0 = r+bias+pbu[n], out1 = r+bias+pbv[n]   (Q projection)
// ---------------------------------------------------------------------------
__global__ __launch_bounds__(256)
void gemm_proj(const float* __restrict__ A, const float* __restrict__ W,
               const float* __restrict__ bias,
               float* __restrict__ out0, float* __restrict__ out1,
               const float* __restrict__ pbu, const float* __restrict__ pbv,
               int M, int mode)
{
    __shared__ float As[16][132];   // [k][m], padded stride
    __shared__ float Bs[16][132];   // [k][n]
    const int tid = threadIdx.x;
    const int ty = tid >> 4, tx = tid & 15;
    const int m0 = blockIdx.y * 128;
    const int n0 = blockIdx.x * 128;

    float acc[8][8];
    #pragma unroll
    for (int i = 0; i < 8; ++i)
        #pragma unroll
        for (int j = 0; j < 8; ++j) acc[i][j] = 0.f;

    for (int kt = 0; kt < D_; kt += 16) {
        // stage A tile (128 rows x 16 k), transposed into As[k][m]
        #pragma unroll
        for (int u = 0; u < 2; ++u) {
            int f = tid + 256*u;          // float4 id 0..511
            int r = f >> 2;               // 0..127
            int c4 = (f & 3) << 2;        // 0,4,8,12
            float4 va;
            if (m0 + r < M) va = *(const float4*)&A[(size_t)(m0 + r)*D_ + kt + c4];
            else            va = make_float4(0.f, 0.f, 0.f, 0.f);
            As[c4+0][r] = va.x; As[c4+1][r] = va.y; As[c4+2][r] = va.z; As[c4+3][r] = va.w;
        }
        // stage B tile (16 k x 128 n)
        #pragma unroll
        for (int u = 0; u < 2; ++u) {
            int f = tid + 256*u;
            int r = f >> 5;               // 0..15
            int c = (f & 31) << 2;        // 0..124
            *(float4*)&Bs[r][c] = *(const float4*)&W[(size_t)(kt + r)*D_ + n0 + c];
        }
        __syncthreads();
        #pragma unroll
        for (int kk = 0; kk < 16; ++kk) {
            float4 a0 = *(float4*)&As[kk][4*ty];
            float4 a1 = *(float4*)&As[kk][4*ty + 64];
            float4 b0 = *(float4*)&Bs[kk][4*tx];
            float4 b1 = *(float4*)&Bs[kk][4*tx + 64];
            float av[8] = {a0.x,a0.y,a0.z,a0.w, a1.x,a1.y,a1.z,a1.w};
            float bv[8] = {b0.x,b0.y,b0.z,b0.w, b1.x,b1.y,b1.z,b1.w};
            #pragma unroll
            for (int i = 0; i < 8; ++i)
                #pragma unroll
                for (int j = 0; j < 8; ++j)
                    acc[i][j] = fmaf(av[i], bv[j], acc[i][j]);
        }
        __syncthreads();
    }

    #pragma unroll
    for (int ib = 0; ib < 2; ++ib) {
        #pragma unroll
        for (int i = 0; i < 4; ++i) {
            int m = m0 + 4*ty + 64*ib + i;
            if (m >= M) continue;
            #pragma unroll
            for (int jb = 0; jb < 2; ++jb) {
                int n = n0 + 4*tx + 64*jb;
                float4 r = make_float4(acc[ib*4+i][jb*4+0], acc[ib*4+i][jb*4+1],
                                       acc[ib*4+i][jb*4+2], acc[ib*4+i][jb*4+3]);
                if (bias) {
                    float4 bb = *(const float4*)&bias[n];
                    r.x += bb.x; r.y += bb.y; r.z += bb.z; r.w += bb.w;
                }
                if (mode == 1) {
                    float4 u4 = *(const float4*)&pbu[n];
                    float4 v4 = *(const float4*)&pbv[n];
                    float4 r0 = make_float4(r.x+u4.x, r.y+u4.y, r.z+u4.z, r.w+u4.w);
                    float4 r1 = make_float4(r.x+v4.x, r.y+v4.y, r.z+v4.z, r.w+v4.w);
                    *(float4*)&out0[(size_t)m*D_ + n] = r0;
                    *(float4*)&out1[(size_t)m*D_ + n] = r1;
                } else {
                    *(float4*)&out0[(size_t)m*D_ + n] = r;
                }
            }
        }
    }
}

// ---------------------------------------------------------------------------
// scores[b,h,t,s] = SCALE*(qu[t]·k[s]) + (mask? NEG_INF : SCALE*(qv[t]·p[s+T-1-t]))
// 32x32 output tile per block; P window of 63 rows staged in LDS; DK chunked by 64.
// thread (ty,tx) owns t in {ty, ty+16}, s in {tx, tx+16}.
// ---------------------------------------------------------------------------
__global__ __launch_bounds__(256)
void attn_scores(const float* __restrict__ qu, const float* __restrict__ qv,
                 const float* __restrict__ kb, const float* __restrict__ pb,
                 const unsigned char* __restrict__ mask,
                 float* __restrict__ scores, int b0)
{
    __shared__ float su[32][68], sv[32][68], sk[32][68], sp[63][68];
    const int tid = threadIdx.x;
    const int ty = tid >> 4, tx = tid & 15;
    const int s0 = blockIdx.x * 32, t0 = blockIdx.y * 32;
    const int bz = blockIdx.z;
    const int lb = bz / H_, h = bz % H_;
    const int b  = b0 + lb;
    const int jb_ = s0 - t0 + (T_ - 1) - 31;   // window base; rows jb_..jb_+62, always in [0,P)

    const float* quB = qu + (size_t)(b*T_ + t0)*D_ + h*DK_;
    const float* qvB = qv + (size_t)(b*T_ + t0)*D_ + h*DK_;
    const float* kB  = kb + (size_t)(b*T_ + s0)*D_ + h*DK_;
    const float* pB  = pb + (size_t)jb_*D_ + h*DK_;

    float aac[2][2] = {{0.f,0.f},{0.f,0.f}};
    float abd[2][2] = {{0.f,0.f},{0.f,0.f}};

    for (int dc = 0; dc < DK_; dc += 64) {
        #pragma unroll
        for (int u = 0; u < 2; ++u) {
            int f = tid + 256*u; int r = f >> 4; int c = (f & 15) << 2;
            *(float4*)&su[r][c] = *(const float4*)&quB[(size_t)r*D_ + dc + c];
            *(float4*)&sv[r][c] = *(const float4*)&qvB[(size_t)r*D_ + dc + c];
            *(float4*)&sk[r][c] = *(const float4*)&kB [(size_t)r*D_ + dc + c];
        }
        #pragma unroll
        for (int u = 0; u < 4; ++u) {
            int f = tid + 256*u;
            if (f < 1008) {  // 63 rows * 16 float4
                int r = f >> 4; int c = (f & 15) << 2;
                *(float4*)&sp[r][c] = *(const float4*)&pB[(size_t)r*D_ + dc + c];
            }
        }
        __syncthreads();
        const int rm = tx - ty;   // in [-15,15]
        #pragma unroll
        for (int kq = 0; kq < 16; ++kq) {
            float4 au0 = *(float4*)&su[ty][4*kq];
            float4 au1 = *(float4*)&su[ty+16][4*kq];
            float4 av0 = *(float4*)&sv[ty][4*kq];
            float4 av1 = *(float4*)&sv[ty+16][4*kq];
            float4 bk0 = *(float4*)&sk[tx][4*kq];
            float4 bk1 = *(float4*)&sk[tx+16][4*kq];
            float4 p15 = *(float4*)&sp[rm+15][4*kq];   // jl = s-t+31: (t+16,s)   -> 15
            float4 p31 = *(float4*)&sp[rm+31][4*kq];   //              (t,s),(t+16,s+16) -> 31
            float4 p47 = *(float4*)&sp[rm+47][4*kq];   //              (t,s+16) -> 47
            aac[0][0] += dot4(au0,bk0);  abd[0][0] += dot4(av0,p31);
            aac[0][1] += dot4(au0,bk1);  abd[0][1] += dot4(av0,p47);
            aac[1][0] += dot4(au1,bk0);  abd[1][0] += dot4(av1,p15);
            aac[1][1] += dot4(au1,bk1);  abd[1][1] += dot4(av1,p31);
        }
        __syncthreads();
    }

    float* so = scores + ((size_t)(lb*H_ + h)*T_ + t0)*T_ + s0;
    const unsigned char* mrow = mask + ((size_t)b*T_ + t0)*T_ + s0;
    #pragma unroll
    for (int i = 0; i < 2; ++i)
        #pragma unroll
        for (int j = 0; j < 2; ++j) {
            int tl = ty + 16*i, sl = tx + 16*j;
            unsigned char mk = mrow[(size_t)tl*T_ + sl];
            float val = aac[i][j]*SCALE_F + (mk ? NEG_INF_F : abd[i][j]*SCALE_F);
            so[(size_t)tl*T_ + sl] = val;
        }
}

// ---------------------------------------------------------------------------
// Row softmax over s (1024), in place. All-masked rows -> probs = 0.
// One block (256 threads) per row; 4 elements/thread.
// ---------------------------------------------------------------------------
__global__ __launch_bounds__(256)
void softmax_rows(float* __restrict__ scores, const unsigned char* __restrict__ mask, int b0)
{
    const int t = blockIdx.x, h = blockIdx.y, lb = blockIdx.z;
    const int b = b0 + lb;
    float* row = scores + ((size_t)(lb*H_ + h)*T_ + t)*T_;
    const unsigned char* mrow = mask + ((size_t)b*T_ + t)*T_;
    const int tid = threadIdx.x;

    float4 v = *(float4*)&row[tid*4];
    uchar4 mk = *(const uchar4*)&mrow[tid*4];
    int nm = (mk.x!=0) + (mk.y!=0) + (mk.z!=0) + (mk.w!=0);
    float mx = fmaxf(fmaxf(v.x,v.y), fmaxf(v.z,v.w));
    #pragma unroll
    for (int off = 32; off; off >>= 1) {
        mx = fmaxf(mx, __shfl_xor(mx, off));
        nm += __shfl_xor(nm, off);
    }
    __shared__ float wred[4];
    __shared__ int   wcnt[4];
    __shared__ float wsum[4];
    const int wv = tid >> 6, ln = tid & 63;
    if (ln == 0) { wred[wv] = mx; wcnt[wv] = nm; }
    __syncthreads();
    mx = fmaxf(fmaxf(wred[0],wred[1]), fmaxf(wred[2],wred[3]));
    const int totm = wcnt[0] + wcnt[1] + wcnt[2] + wcnt[3];

    float e0 = __expf(v.x - mx), e1 = __expf(v.y - mx);
    float e2 = __expf(v.z - mx), e3 = __expf(v.w - mx);
    float s = e0 + e1 + e2 + e3;
    #pragma unroll
    for (int off = 32; off; off >>= 1) s += __shfl_xor(s, off);
    if (ln == 0) wsum[wv] = s;
    __syncthreads();
    s = wsum[0] + wsum[1] + wsum[2] + wsum[3];

    const float inv = (totm == T_) ? 0.f : 1.f / s;
    *(float4*)&row[tid*4] = make_float4(e0*inv, e1*inv, e2*inv, e3*inv);
}

// ---------------------------------------------------------------------------
// ctx[b, t, h*DK+n] = sum_s probs[lb,h,t,s] * v[b, s, h*DK+n]
// M=1024(t) x N=128(n) x K=1024(s); 64x64 tile, BK=16, 4x4/thread.
// ---------------------------------------------------------------------------
__global__ __launch_bounds__(256)
void attn_pv(const float* __restrict__ probs, const float* __restrict__ vbuf,
             float* __restrict__ ctx, int b0)
{
    __shared__ float As[16][68];   // [k][t]
    __shared__ float Bs[16][68];   // [k][n]
    const int tid = threadIdx.x;
    const int ty = tid >> 4, tx = tid & 15;
    const int n0 = blockIdx.x * 64;
    const int t0 = blockIdx.y * 64;
    const int bz = blockIdx.z;
    const int lb = bz / H_, h = bz % H_;
    const int b  = b0 + lb;

    const float* A  = probs + (size_t)(lb*H_ + h)*T_*T_;
    const float* Bv = vbuf + (size_t)(b*T_)*D_ + h*DK_ + n0;

    float acc[4][4];
    #pragma unroll
    for (int i = 0; i < 4; ++i)
        #pragma unroll
        for (int j = 0; j < 4; ++j) acc[i][j] = 0.f;

    for (int kt = 0; kt < T_; kt += 16) {
        {   // A tile: 64 t-rows x 16 s, transposed
            int r = tid >> 2, c4 = (tid & 3) << 2;
            float4 va = *(const float4*)&A[(size_t)(t0 + r)*T_ + kt + c4];
            As[c4+0][r] = va.x; As[c4+1][r] = va.y; As[c4+2][r] = va.z; As[c4+3][r] = va.w;
        }
        {   // B tile: 16 s-rows x 64 n
            int r = tid >> 4, c = (tid & 15) << 2;
            *(float4*)&Bs[r][c] = *(const float4*)&Bv[(size_t)(kt + r)*D_ + c];
        }
        __syncthreads();
        #pragma unroll
        for (int kk = 0; kk < 16; ++kk) {
            float4 a  = *(float4*)&As[kk][4*ty];
            float4 bq = *(float4*)&Bs[kk][4*tx];
            float av[4] = {a.x,a.y,a.z,a.w};
            float bv4[4] = {bq.x,bq.y,bq.z,bq.w};
            #pragma unroll
            for (int i = 0; i < 4; ++i)
                #pragma unroll
                for (int j = 0; j < 4; ++j)
                    acc[i][j] = fmaf(av[i], bv4[j], acc[i][j]);
        }
        __syncthreads();
    }
    #pragma unroll
    for (int i = 0; i < 4; ++i) {
        *(float4*)&ctx[(size_t)(b*T_ + t0 + 4*ty + i)*D_ + h*DK_ + n0 + 4*tx] =
            make_float4(acc[i][0], acc[i][1], acc[i][2], acc[i][3]);
    }
}

// ---------------------------------------------------------------------------
extern "C" void kernel_launch(void* const* d_in, const int* in_sizes, int n_in,
                              void* d_out, int out_size, void* d_ws, size_t ws_size,
                              hipStream_t stream)
{
    const float* query   = (const float*)d_in[0];
    const float* key     = (const float*)d_in[1];
    const float* value   = (const float*)d_in[2];
    const float* pos_emb = (const float*)d_in[3];
    const unsigned char* mask = (const unsigned char*)d_in[4];
    const float* Wq  = (const float*)d_in[5];
    const float* bq  = (const float*)d_in[6];
    const float* Wk  = (const float*)d_in[7];
    const float* bk  = (const float*)d_in[8];
    const float* Wv  = (const float*)d_in[9];
    const float* bv  = (const float*)d_in[10];
    const float* Wp  = (const float*)d_in[11];
    const float* Wo  = (const float*)d_in[12];
    const float* bo  = (const float*)d_in[13];
    const float* pbu = (const float*)d_in[14];
    const float* pbv = (const float*)d_in[15];
    float* out = (float*)d_out;

    float* ws  = (float*)d_ws;
    const size_t SZ_BTD = (size_t)B_ * T_ * D_;     // 4,194,304
    float* qu  = ws;
    float* qv  = qu  + SZ_BTD;
    float* kb  = qv  + SZ_BTD;
    float* vb  = kb  + SZ_BTD;
    float* ctx = vb  + SZ_BTD;
    float* pb  = ctx + SZ_BTD;                      // P_*D_ = 2,096,128
    float* scores = pb + (size_t)P_ * D_;

    // adaptive batch-chunking of the scores buffer by available workspace
    const size_t base_bytes = ((size_t)(5*SZ_BTD) + (size_t)P_*D_) * sizeof(float);
    const size_t per_b = (size_t)H_ * T_ * T_;      // floats per batch of scores
    int SB = 1;
    if (ws_size > base_bytes) {
        size_t rem = (ws_size - base_bytes) / sizeof(float);
        SB = (int)(rem / per_b);
        if (SB < 1) SB = 1;
        if (SB > B_) SB = B_;
    }

    // projections
    gemm_proj<<<dim3(8, 32), 256, 0, stream>>>(query, Wq, bq, qu, qv, pbu, pbv, B_*T_, 1);
    gemm_proj<<<dim3(8, 32), 256, 0, stream>>>(key,   Wk, bk, kb, nullptr, nullptr, nullptr, B_*T_, 0);
    gemm_proj<<<dim3(8, 32), 256, 0, stream>>>(value, Wv, bv, vb, nullptr, nullptr, nullptr, B_*T_, 0);
    gemm_proj<<<dim3(8, 16), 256, 0, stream>>>(pos_emb, Wp, nullptr, pb, nullptr, nullptr, nullptr, P_, 0);

    // attention per batch chunk
    for (int b0 = 0; b0 < B_; b0 += SB) {
        int nb = B_ - b0; if (nb > SB) nb = SB;
        attn_scores <<<dim3(32, 32, nb*H_), 256, 0, stream>>>(qu, qv, kb, pb, mask, scores, b0);
        softmax_rows<<<dim3(T_, H_, nb),   256, 0, stream>>>(scores, mask, b0);
        attn_pv     <<<dim3(2, 16, nb*H_), 256, 0, stream>>>(scores, vb, ctx, b0);
    }

    // output projection
    gemm_proj<<<dim3(8, 32), 256, 0, stream>>>(ctx, Wo, bo, out, nullptr, nullptr, nullptr, B_*T_, 0);
}

// Round 3
// 611.731 us; speedup vs baseline: 2.8996x; 2.8996x over previous
//
#include <hip/hip_runtime.h>
#include <cstddef>

// RelPositionMultiHeadAttention — round 3: resubmission of round-2 bf16 MFMA
// pipeline (round-2 bench never ran: GPU acquisition timeout).
// B=4, T=1024, D=1024, H=8, DK=128, P=2047 (padded to 2048 ld).
//
// Pipeline:
//   casts: query/key/value/pos_emb fp32->bf16; W* fp32[K,N] -> bf16 [N,K] (transposed)
//   gemm_proj_bt<1>: qu = x@Wq+bq+pbu, qv = ..+pbv  (bf16 out)
//   gemm_proj_bt<0>: k, v (bias, bf16 out)
//   gemm_proj_bt<3>: p = pos@Wp (no bias, bf16 out, M=2047)
//   vt_trans: v [B,T,D] -> vT [B,H,DK,T]
//   per b-chunk (adaptive SB from ws_size):
//     gemm_bd: bd_raw[lb,h,t,j] = qv.p  (M=1024,N=2047->2048,K=128), bf16
//     attn_scores_mfma: scores = SCALE*qu.k + (mask? NEG_INF : SCALE*bd[t, s+1023-t]) fp32
//     softmax_rows: fp32 softmax -> bf16 probs (all-masked row -> 0)
//     attn_pv_mfma: ctx[b,t,h*128+n] = probs @ vT  (bf16 out)
//   gemm_proj_bt<2>: out = ctx@Wo + bo (fp32 out)
//
// GEMM structure (m97-style): 128x128 tile, BK=64, 256 thr = 4 waves (2x2 of 64x64),
// global_load_lds width=16 into linear LDS [128][64] bf16, ds_read_b128 fragments,
// v_mfma_f32_16x16x32_bf16, fp32 accum.

#define B_ 4
#define T_ 1024
#define D_ 1024
#define H_ 8
#define DK_ 128
#define P_ 2047
#define PLD_ 2048
#define SCALE_F 0.08838834764831845f
#define NEG_INF_F (-10000.0f)

typedef unsigned short ushort_t;
typedef __attribute__((ext_vector_type(8))) short short8;
typedef __attribute__((ext_vector_type(8))) unsigned short ushortx8;
typedef __attribute__((ext_vector_type(4))) float f32x4;

__device__ __forceinline__ ushort_t f2bf(float f) {
    unsigned u = __float_as_uint(f);
    unsigned r = (u + 0x7FFFu + ((u >> 16) & 1u)) >> 16;   // RNE
    return (ushort_t)r;
}
__device__ __forceinline__ float bf2f(ushort_t b) {
    return __uint_as_float(((unsigned)b) << 16);
}

__device__ __forceinline__ void gload_lds16(const ushort_t* src, ushort_t* dst) {
    __builtin_amdgcn_global_load_lds(
        (const __attribute__((address_space(1))) unsigned int*)src,
        (__attribute__((address_space(3))) unsigned int*)dst, 16, 0, 0);
}

// Stage a 128x64 bf16 tile: rows rowBase..rowBase+127 (clamped to rowMax-1),
// cols k0..k0+63 of a [*, ldg] bf16 matrix, into linear LDS [128][64].
__device__ __forceinline__ void stage128x64(const ushort_t* __restrict__ g, int ldg,
                                            int rowBase, int rowMax,
                                            ushort_t* lds, int k0)
{
    const int tid = threadIdx.x;
    const int w = tid >> 6;
    #pragma unroll
    for (int u = 0; u < 4; ++u) {
        int e = tid * 8 + u * 2048;          // element index in tile
        int row = e >> 6, col = e & 63;
        int gr = rowBase + row; if (gr > rowMax - 1) gr = rowMax - 1;
        const ushort_t* src = g + (size_t)gr * ldg + k0 + col;
        ushort_t* dst = lds + w * 512 + u * 2048;   // wave-uniform base; HW adds lane*16B
        gload_lds16(src, dst);
    }
}

// 4 waves, wave (w>>1, w&1) owns 64x64; 2 k-steps of 32; 16 MFMA each.
__device__ __forceinline__ void mma128(const ushort_t* As, const ushort_t* Bs, f32x4 acc[4][4])
{
    const int lane = threadIdx.x & 63;
    const int w = threadIdx.x >> 6;
    const int wr = (w >> 1) * 64, wc = (w & 1) * 64;
    const int lr = lane & 15, lk = (lane >> 4) * 8;
    #pragma unroll
    for (int kk = 0; kk < 2; ++kk) {
        short8 a[4], b[4];
        #pragma unroll
        for (int i = 0; i < 4; ++i)
            a[i] = *(const short8*)&As[(size_t)(wr + i * 16 + lr) * 64 + kk * 32 + lk];
        #pragma unroll
        for (int j = 0; j < 4; ++j)
            b[j] = *(const short8*)&Bs[(size_t)(wc + j * 16 + lr) * 64 + kk * 32 + lk];
        #pragma unroll
        for (int i = 0; i < 4; ++i)
            #pragma unroll
            for (int j = 0; j < 4; ++j)
                acc[i][j] = __builtin_amdgcn_mfma_f32_16x16x32_bf16(a[i], b[j], acc[i][j], 0, 0, 0);
    }
}

#define ACC_DECL f32x4 acc[4][4]; \
    _Pragma("unroll") for (int i_ = 0; i_ < 4; ++i_) \
    _Pragma("unroll") for (int j_ = 0; j_ < 4; ++j_) \
    _Pragma("unroll") for (int r_ = 0; r_ < 4; ++r_) acc[i_][j_][r_] = 0.f;

#define EPI_COORDS \
    const int lane = threadIdx.x & 63; \
    const int w = threadIdx.x >> 6; \
    const int wr = (w >> 1) * 64, wc = (w & 1) * 64; \
    const int lcol = lane & 15, lrow4 = (lane >> 4) * 4;

// ---------------------------------------------------------------------------
// Projection GEMM: C[M,1024] = A_bf16[M,1024] @ Bt_bf16[1024,1024]^T
// MODE 0: bf16 out = acc+bias ; MODE 1: dual bf16 out (+pbu/+pbv)
// MODE 2: fp32 out = acc+bias ; MODE 3: bf16 out = acc (no bias)
// ---------------------------------------------------------------------------
template<int MODE>
__global__ __launch_bounds__(256)
void gemm_proj_bt(const ushort_t* __restrict__ A, const ushort_t* __restrict__ Bt,
                  const float* __restrict__ bias,
                  void* __restrict__ out0, void* __restrict__ out1,
                  const float* __restrict__ pbu, const float* __restrict__ pbv, int M)
{
    __shared__ ushort_t As[128 * 64], Bs[128 * 64];
    const int n0 = blockIdx.x * 128, m0 = blockIdx.y * 128;
    ACC_DECL;
    for (int k0 = 0; k0 < 1024; k0 += 64) {
        stage128x64(A, 1024, m0, M, As, k0);
        stage128x64(Bt, 1024, n0, 1024, Bs, k0);
        __syncthreads();
        mma128(As, Bs, acc);
        __syncthreads();
    }
    EPI_COORDS;
    #pragma unroll
    for (int i = 0; i < 4; ++i)
        #pragma unroll
        for (int j = 0; j < 4; ++j)
            #pragma unroll
            for (int r = 0; r < 4; ++r) {
                int m = m0 + wr + i * 16 + lrow4 + r;
                int n = n0 + wc + j * 16 + lcol;
                if (m >= M) continue;
                float v = acc[i][j][r];
                size_t o = (size_t)m * 1024 + n;
                if (MODE == 0) { ((ushort_t*)out0)[o] = f2bf(v + bias[n]); }
                else if (MODE == 1) {
                    v += bias[n];
                    ((ushort_t*)out0)[o] = f2bf(v + pbu[n]);
                    ((ushort_t*)out1)[o] = f2bf(v + pbv[n]);
                } else if (MODE == 2) { ((float*)out0)[o] = v + bias[n]; }
                else { ((ushort_t*)out0)[o] = f2bf(v); }
            }
}

// ---------------------------------------------------------------------------
// bd_raw[lb,h,t,j] = qv[b,t,h*128+:] . p[j,h*128+:]   (K=128), bf16 out ld=2048
// grid (16, 8, nb*H)
// ---------------------------------------------------------------------------
__global__ __launch_bounds__(256)
void gemm_bd(const ushort_t* __restrict__ qv, const ushort_t* __restrict__ p,
             ushort_t* __restrict__ bd, int b0)
{
    __shared__ ushort_t As[128 * 64], Bs[128 * 64];
    const int j0 = blockIdx.x * 128, t0 = blockIdx.y * 128;
    const int lb = blockIdx.z >> 3, h = blockIdx.z & 7;
    const int b = b0 + lb;
    const ushort_t* Ab = qv + (size_t)b * T_ * D_ + h * DK_;
    const ushort_t* Bb = p + h * DK_;
    ACC_DECL;
    for (int k0 = 0; k0 < DK_; k0 += 64) {
        stage128x64(Ab, D_, t0, T_, As, k0);
        stage128x64(Bb, D_, j0, P_, Bs, k0);     // row 2047 clamped to 2046
        __syncthreads();
        mma128(As, Bs, acc);
        __syncthreads();
    }
    EPI_COORDS;
    ushort_t* ob = bd + ((size_t)(lb * H_ + h) * T_) * PLD_;
    #pragma unroll
    for (int i = 0; i < 4; ++i)
        #pragma unroll
        for (int j = 0; j < 4; ++j)
            #pragma unroll
            for (int r = 0; r < 4; ++r) {
                int t = t0 + wr + i * 16 + lrow4 + r;
                int jj = j0 + wc + j * 16 + lcol;
                if (jj < P_) ob[(size_t)t * PLD_ + jj] = f2bf(acc[i][j][r]);
            }
}

// ---------------------------------------------------------------------------
// scores[lb,h,t,s] = SCALE*(qu.k) + (mask? NEG_INF : SCALE*bd[t, s+1023-t])
// grid (8, 8, nb*H), K=128
// ---------------------------------------------------------------------------
__global__ __launch_bounds__(256)
void attn_scores_mfma(const ushort_t* __restrict__ qu, const ushort_t* __restrict__ kb,
                      const ushort_t* __restrict__ bd, const unsigned char* __restrict__ mask,
                      float* __restrict__ scores, int b0)
{
    __shared__ ushort_t As[128 * 64], Bs[128 * 64];
    const int s0 = blockIdx.x * 128, t0 = blockIdx.y * 128;
    const int lb = blockIdx.z >> 3, h = blockIdx.z & 7;
    const int b = b0 + lb;
    const ushort_t* Ab = qu + (size_t)b * T_ * D_ + h * DK_;
    const ushort_t* Bb = kb + (size_t)b * T_ * D_ + h * DK_;
    ACC_DECL;
    for (int k0 = 0; k0 < DK_; k0 += 64) {
        stage128x64(Ab, D_, t0, T_, As, k0);
        stage128x64(Bb, D_, s0, T_, Bs, k0);
        __syncthreads();
        mma128(As, Bs, acc);
        __syncthreads();
    }
    EPI_COORDS;
    const ushort_t* bdb = bd + ((size_t)(lb * H_ + h) * T_) * PLD_;
    float* sb = scores + ((size_t)(lb * H_ + h) * T_) * T_;
    const unsigned char* mb = mask + (size_t)b * T_ * T_;
    #pragma unroll
    for (int i = 0; i < 4; ++i)
        #pragma unroll
        for (int j = 0; j < 4; ++j)
            #pragma unroll
            for (int r = 0; r < 4; ++r) {
                int t = t0 + wr + i * 16 + lrow4 + r;
                int s = s0 + wc + j * 16 + lcol;
                float ac = acc[i][j][r] * SCALE_F;
                ushort_t bdv = bdb[(size_t)t * PLD_ + (s + T_ - 1 - t)];
                unsigned char mk = mb[(size_t)t * T_ + s];
                sb[(size_t)t * T_ + s] = ac + (mk ? NEG_INF_F : bf2f(bdv) * SCALE_F);
            }
}

// ---------------------------------------------------------------------------
// Row softmax fp32 -> bf16 probs. All-masked row -> 0. grid (T, H, nb)
// ---------------------------------------------------------------------------
__global__ __launch_bounds__(256)
void softmax_rows(const float* __restrict__ scores, ushort_t* __restrict__ probs,
                  const unsigned char* __restrict__ mask, int b0)
{
    const int t = blockIdx.x, h = blockIdx.y, lb = blockIdx.z;
    const int b = b0 + lb;
    const float* row = scores + ((size_t)(lb * H_ + h) * T_ + t) * T_;
    ushort_t* prow = probs + ((size_t)(lb * H_ + h) * T_ + t) * T_;
    const unsigned char* mrow = mask + ((size_t)b * T_ + t) * T_;
    const int tid = threadIdx.x;

    float4 v = *(const float4*)&row[tid * 4];
    uchar4 mk = *(const uchar4*)&mrow[tid * 4];
    int nm = (mk.x != 0) + (mk.y != 0) + (mk.z != 0) + (mk.w != 0);
    float mx = fmaxf(fmaxf(v.x, v.y), fmaxf(v.z, v.w));
    #pragma unroll
    for (int off = 32; off; off >>= 1) {
        mx = fmaxf(mx, __shfl_xor(mx, off));
        nm += __shfl_xor(nm, off);
    }
    __shared__ float wred[4]; __shared__ int wcnt[4]; __shared__ float wsum[4];
    const int wv = tid >> 6, ln = tid & 63;
    if (ln == 0) { wred[wv] = mx; wcnt[wv] = nm; }
    __syncthreads();
    mx = fmaxf(fmaxf(wred[0], wred[1]), fmaxf(wred[2], wred[3]));
    const int totm = wcnt[0] + wcnt[1] + wcnt[2] + wcnt[3];

    float e0 = __expf(v.x - mx), e1 = __expf(v.y - mx);
    float e2 = __expf(v.z - mx), e3 = __expf(v.w - mx);
    float s = e0 + e1 + e2 + e3;
    #pragma unroll
    for (int off = 32; off; off >>= 1) s += __shfl_xor(s, off);
    if (ln == 0) wsum[wv] = s;
    __syncthreads();
    s = wsum[0] + wsum[1] + wsum[2] + wsum[3];

    const float inv = (totm == T_) ? 0.f : 1.f / s;
    ushort_t r0 = f2bf(e0 * inv), r1 = f2bf(e1 * inv), r2 = f2bf(e2 * inv), r3 = f2bf(e3 * inv);
    unsigned p01 = (unsigned)r0 | ((unsigned)r1 << 16);
    unsigned p23 = (unsigned)r2 | ((unsigned)r3 << 16);
    *(uint2*)&prow[tid * 4] = make_uint2(p01, p23);
}

// ---------------------------------------------------------------------------
// ctx[b,t,h*128+n] = probs[lb,h,t,:] @ vT[b,h,n,:]   (K=1024), bf16 out
// grid (1, 8, nb*H)
// ---------------------------------------------------------------------------
__global__ __launch_bounds__(256)
void attn_pv_mfma(const ushort_t* __restrict__ probs, const ushort_t* __restrict__ vT,
                  ushort_t* __restrict__ ctx, int b0)
{
    __shared__ ushort_t As[128 * 64], Bs[128 * 64];
    const int t0 = blockIdx.y * 128;
    const int lb = blockIdx.z >> 3, h = blockIdx.z & 7;
    const int b = b0 + lb;
    const ushort_t* Ab = probs + (size_t)(lb * H_ + h) * T_ * T_;
    const ushort_t* Bb = vT + (size_t)(b * H_ + h) * DK_ * T_;
    ACC_DECL;
    for (int k0 = 0; k0 < T_; k0 += 64) {
        stage128x64(Ab, T_, t0, T_, As, k0);
        stage128x64(Bb, T_, 0, DK_, Bs, k0);
        __syncthreads();
        mma128(As, Bs, acc);
        __syncthreads();
    }
    EPI_COORDS;
    #pragma unroll
    for (int i = 0; i < 4; ++i)
        #pragma unroll
        for (int j = 0; j < 4; ++j)
            #pragma unroll
            for (int r = 0; r < 4; ++r) {
                int t = t0 + wr + i * 16 + lrow4 + r;
                int n = wc + j * 16 + lcol;
                if (n < DK_)
                    ctx[((size_t)b * T_ + t) * D_ + h * DK_ + n] = f2bf(acc[i][j][r]);
            }
}

// ---------------------------------------------------------------------------
// casts / transposes
// ---------------------------------------------------------------------------
__global__ __launch_bounds__(256)
void cast_bf16(const float* __restrict__ in, ushort_t* __restrict__ out, int n)
{
    int i = (blockIdx.x * 256 + threadIdx.x) * 8;
    if (i >= n) return;
    float4 a = *(const float4*)&in[i];
    float4 bq = *(const float4*)&in[i + 4];
    ushortx8 r;
    r[0] = f2bf(a.x); r[1] = f2bf(a.y); r[2] = f2bf(a.z); r[3] = f2bf(a.w);
    r[4] = f2bf(bq.x); r[5] = f2bf(bq.y); r[6] = f2bf(bq.z); r[7] = f2bf(bq.w);
    *(ushortx8*)&out[i] = r;
}

// W fp32 [K=1024, N=1024] -> Wt bf16 [N, K]
__global__ __launch_bounds__(256)
void wt_cast(const float* __restrict__ W, ushort_t* __restrict__ Wt)
{
    __shared__ float tile[32][33];
    const int n0 = blockIdx.x * 32, k0 = blockIdx.y * 32;
    const int lx = threadIdx.x & 31, ly = threadIdx.x >> 5;
    #pragma unroll
    for (int r = 0; r < 32; r += 8)
        tile[ly + r][lx] = W[(size_t)(k0 + ly + r) * 1024 + n0 + lx];
    __syncthreads();
    #pragma unroll
    for (int r = 0; r < 32; r += 8)
        Wt[(size_t)(n0 + ly + r) * 1024 + k0 + lx] = f2bf(tile[lx][ly + r]);
}

// v bf16 [B,T,D] -> vT bf16 [B,H,DK,T]
__global__ __launch_bounds__(256)
void vt_trans(const ushort_t* __restrict__ v, ushort_t* __restrict__ vT)
{
    __shared__ ushort_t tile[32][33];
    const int t0 = blockIdx.x * 32, n0 = blockIdx.y * 32;
    const int bh = blockIdx.z;
    const int b = bh >> 3, h = bh & 7;
    const int lx = threadIdx.x & 31, ly = threadIdx.x >> 5;
    const ushort_t* src = v + (size_t)b * T_ * D_ + h * DK_;
    #pragma unroll
    for (int r = 0; r < 32; r += 8)
        tile[ly + r][lx] = src[(size_t)(t0 + ly + r) * D_ + n0 + lx];
    __syncthreads();
    ushort_t* dst = vT + (size_t)bh * DK_ * T_;
    #pragma unroll
    for (int r = 0; r < 32; r += 8)
        dst[(size_t)(n0 + ly + r) * T_ + t0 + lx] = tile[lx][ly + r];
}

// ---------------------------------------------------------------------------
extern "C" void kernel_launch(void* const* d_in, const int* in_sizes, int n_in,
                              void* d_out, int out_size, void* d_ws, size_t ws_size,
                              hipStream_t stream)
{
    const float* query   = (const float*)d_in[0];
    const float* key     = (const float*)d_in[1];
    const float* value   = (const float*)d_in[2];
    const float* pos_emb = (const float*)d_in[3];
    const unsigned char* mask = (const unsigned char*)d_in[4];
    const float* Wq  = (const float*)d_in[5];
    const float* bq  = (const float*)d_in[6];
    const float* Wk  = (const float*)d_in[7];
    const float* bk  = (const float*)d_in[8];
    const float* Wv  = (const float*)d_in[9];
    const float* bv  = (const float*)d_in[10];
    const float* Wp  = (const float*)d_in[11];
    const float* Wo  = (const float*)d_in[12];
    const float* bo  = (const float*)d_in[13];
    const float* pbu = (const float*)d_in[14];
    const float* pbv = (const float*)d_in[15];
    float* out = (float*)d_out;

    const size_t SZ_BTD = (size_t)B_ * T_ * D_;       // 4,194,304
    const size_t SZ_PD  = (size_t)P_ * D_;            // 2,096,128
    const size_t SZ_W   = (size_t)D_ * D_;            // 1,048,576

    ushort_t* c = (ushort_t*)d_ws;
    ushort_t* qbf  = c; c += SZ_BTD;
    ushort_t* kbfi = c; c += SZ_BTD;
    ushort_t* vbfi = c; c += SZ_BTD;
    ushort_t* pbf  = c; c += SZ_PD;
    ushort_t* WqT = c; c += SZ_W;
    ushort_t* WkT = c; c += SZ_W;
    ushort_t* WvT = c; c += SZ_W;
    ushort_t* WpT = c; c += SZ_W;
    ushort_t* WoT = c; c += SZ_W;
    ushort_t* qu  = c; c += SZ_BTD;
    ushort_t* qv  = c; c += SZ_BTD;
    ushort_t* kb  = c; c += SZ_BTD;
    ushort_t* vb  = c; c += SZ_BTD;
    ushort_t* ctx = c; c += SZ_BTD;
    ushort_t* vT  = c; c += SZ_BTD;
    ushort_t* pp  = c; c += SZ_PD;

    const size_t base_bytes = (size_t)((char*)c - (char*)d_ws);
    const size_t per_b = (size_t)H_ * T_ * PLD_ * 2    // bd bf16
                       + (size_t)H_ * T_ * T_ * 4      // scores fp32
                       + (size_t)H_ * T_ * T_ * 2;     // probs bf16
    int SB = 1;
    if (ws_size > base_bytes) {
        size_t sb = (ws_size - base_bytes) / per_b;
        SB = sb < 1 ? 1 : (sb > B_ ? B_ : (int)sb);
    }
    ushort_t* bd     = c;
    float*    scores = (float*)(bd + (size_t)SB * H_ * T_ * PLD_);
    ushort_t* probs  = (ushort_t*)(scores + (size_t)SB * H_ * T_ * T_);

    // casts
    cast_bf16<<<dim3((int)(SZ_BTD / 8 / 256)), 256, 0, stream>>>(query, qbf, (int)SZ_BTD);
    cast_bf16<<<dim3((int)(SZ_BTD / 8 / 256)), 256, 0, stream>>>(key, kbfi, (int)SZ_BTD);
    cast_bf16<<<dim3((int)(SZ_BTD / 8 / 256)), 256, 0, stream>>>(value, vbfi, (int)SZ_BTD);
    cast_bf16<<<dim3((int)((SZ_PD / 8 + 255) / 256)), 256, 0, stream>>>(pos_emb, pbf, (int)SZ_PD);
    wt_cast<<<dim3(32, 32), 256, 0, stream>>>(Wq, WqT);
    wt_cast<<<dim3(32, 32), 256, 0, stream>>>(Wk, WkT);
    wt_cast<<<dim3(32, 32), 256, 0, stream>>>(Wv, WvT);
    wt_cast<<<dim3(32, 32), 256, 0, stream>>>(Wp, WpT);
    wt_cast<<<dim3(32, 32), 256, 0, stream>>>(Wo, WoT);

    // projections
    gemm_proj_bt<1><<<dim3(8, 32), 256, 0, stream>>>(qbf, WqT, bq, qu, qv, pbu, pbv, B_ * T_);
    gemm_proj_bt<0><<<dim3(8, 32), 256, 0, stream>>>(kbfi, WkT, bk, kb, nullptr, nullptr, nullptr, B_ * T_);
    gemm_proj_bt<0><<<dim3(8, 32), 256, 0, stream>>>(vbfi, WvT, bv, vb, nullptr, nullptr, nullptr, B_ * T_);
    gemm_proj_bt<3><<<dim3(8, 16), 256, 0, stream>>>(pbf, WpT, nullptr, pp, nullptr, nullptr, nullptr, P_);
    vt_trans<<<dim3(32, 4, 32), 256, 0, stream>>>(vb, vT);

    // attention, chunked over batch
    for (int b0 = 0; b0 < B_; b0 += SB) {
        int nb = B_ - b0; if (nb > SB) nb = SB;
        gemm_bd        <<<dim3(16, 8, nb * H_), 256, 0, stream>>>(qv, pp, bd, b0);
        attn_scores_mfma<<<dim3(8, 8, nb * H_), 256, 0, stream>>>(qu, kb, bd, mask, scores, b0);
        softmax_rows   <<<dim3(T_, H_, nb), 256, 0, stream>>>(scores, probs, mask, b0);
        attn_pv_mfma   <<<dim3(1, 8, nb * H_), 256, 0, stream>>>(probs, vT, ctx, b0);
    }

    // output projection (fp32 out)
    gemm_proj_bt<2><<<dim3(8, 32), 256, 0, stream>>>(ctx, WoT, bo, (void*)out, nullptr, nullptr, nullptr, B_ * T_);
}

// Round 4
// 480.821 us; speedup vs baseline: 3.6890x; 1.2723x over previous
//
#include <hip/hip_runtime.h>
#include <cstddef>

// RelPositionMultiHeadAttention — round 4: fused flash attention middle.
// B=4, T=1024, D=1024, H=8, DK=128, P=2047.
//
// Pipeline:
//   casts: query/key/value/pos_emb fp32->bf16; W* fp32[K,N] -> bf16 [N,K]
//   gemm_proj_bt<1>: qu = x@Wq+bq+pbu, qv = ..+pbv  (bf16)
//   gemm_proj_bt<0>: k, v ; <3>: p = pos@Wp (M=2047)
//   vt_trans: v -> vT [B,H,DK,T]
//   per b-chunk:
//     gemm_bd_shifted: bdS[lb,h,t,s] = qv[t].p[s+1023-t]  (rel-shift folded into
//                      the GEMM epilogue store predicate; 67 MB bf16 vs 128 MB)
//     flash_attn: per (t0,b,h) block: acc_s init = mask? NEG/SCALE : bdS (C-operand),
//                 acc_s += qu.k (MFMA), online softmax (cross-wave LDS stats),
//                 P->LDS bf16 (swizzled), acc_o += P@vT (MFMA). ctx out.
//   gemm_proj_bt<2>: out = ctx@Wo + bo (fp32)
//
// flash LDS tiles XOR-swizzled (16B-block ^ (row&7)); staged via pre-swizzled
// global source (global_load_lds dest must stay linear). All-masked-row detect:
// m_final < -5000 (legit scores |.|<~50, masked ~ -10000).

#define B_ 4
#define T_ 1024
#define D_ 1024
#define H_ 8
#define DK_ 128
#define P_ 2047
#define SCALE_F 0.08838834764831845f
#define NEG_INF_F (-10000.0f)

typedef unsigned short ushort_t;
typedef __attribute__((ext_vector_type(8))) short short8;
typedef __attribute__((ext_vector_type(8))) unsigned short ushortx8;
typedef __attribute__((ext_vector_type(4))) float f32x4;

__device__ __forceinline__ ushort_t f2bf(float f) {
    unsigned u = __float_as_uint(f);
    unsigned r = (u + 0x7FFFu + ((u >> 16) & 1u)) >> 16;   // RNE
    return (ushort_t)r;
}
__device__ __forceinline__ float bf2f(ushort_t b) {
    return __uint_as_float(((unsigned)b) << 16);
}

__device__ __forceinline__ void gload_lds16(const ushort_t* src, ushort_t* dst) {
    __builtin_amdgcn_global_load_lds(
        (const __attribute__((address_space(1))) unsigned int*)src,
        (__attribute__((address_space(3))) unsigned int*)dst, 16, 0, 0);
}

// ---------------- 256-thread GEMM building blocks (proven, round 3) ----------
__device__ __forceinline__ void stage128x64(const ushort_t* __restrict__ g, int ldg,
                                            int rowBase, int rowMax,
                                            ushort_t* lds, int k0)
{
    const int tid = threadIdx.x;
    const int w = tid >> 6;
    #pragma unroll
    for (int u = 0; u < 4; ++u) {
        int e = tid * 8 + u * 2048;
        int row = e >> 6, col = e & 63;
        int gr = rowBase + row; if (gr > rowMax - 1) gr = rowMax - 1;
        const ushort_t* src = g + (size_t)gr * ldg + k0 + col;
        ushort_t* dst = lds + w * 512 + u * 2048;   // wave-uniform; HW adds lane*16B
        gload_lds16(src, dst);
    }
}

__device__ __forceinline__ void mma128(const ushort_t* As, const ushort_t* Bs, f32x4 acc[4][4])
{
    const int lane = threadIdx.x & 63;
    const int w = threadIdx.x >> 6;
    const int wr = (w >> 1) * 64, wc = (w & 1) * 64;
    const int lr = lane & 15, lk = (lane >> 4) * 8;
    #pragma unroll
    for (int kk = 0; kk < 2; ++kk) {
        short8 a[4], b[4];
        #pragma unroll
        for (int i = 0; i < 4; ++i)
            a[i] = *(const short8*)&As[(size_t)(wr + i * 16 + lr) * 64 + kk * 32 + lk];
        #pragma unroll
        for (int j = 0; j < 4; ++j)
            b[j] = *(const short8*)&Bs[(size_t)(wc + j * 16 + lr) * 64 + kk * 32 + lk];
        #pragma unroll
        for (int i = 0; i < 4; ++i)
            #pragma unroll
            for (int j = 0; j < 4; ++j)
                acc[i][j] = __builtin_amdgcn_mfma_f32_16x16x32_bf16(a[i], b[j], acc[i][j], 0, 0, 0);
    }
}

#define ACC_DECL f32x4 acc[4][4]; \
    _Pragma("unroll") for (int i_ = 0; i_ < 4; ++i_) \
    _Pragma("unroll") for (int j_ = 0; j_ < 4; ++j_) \
    _Pragma("unroll") for (int r_ = 0; r_ < 4; ++r_) acc[i_][j_][r_] = 0.f;

#define EPI_COORDS \
    const int lane = threadIdx.x & 63; \
    const int w = threadIdx.x >> 6; \
    const int wr = (w >> 1) * 64, wc = (w & 1) * 64; \
    const int lcol = lane & 15, lrow4 = (lane >> 4) * 4;

// ---------------------------------------------------------------------------
// Projection GEMM: C[M,1024] = A_bf16[M,1024] @ Bt_bf16[1024,1024]^T
// ---------------------------------------------------------------------------
template<int MODE>
__global__ __launch_bounds__(256)
void gemm_proj_bt(const ushort_t* __restrict__ A, const ushort_t* __restrict__ Bt,
                  const float* __restrict__ bias,
                  void* __restrict__ out0, void* __restrict__ out1,
                  const float* __restrict__ pbu, const float* __restrict__ pbv, int M)
{
    __shared__ ushort_t As[128 * 64], Bs[128 * 64];
    const int n0 = blockIdx.x * 128, m0 = blockIdx.y * 128;
    ACC_DECL;
    for (int k0 = 0; k0 < 1024; k0 += 64) {
        stage128x64(A, 1024, m0, M, As, k0);
        stage128x64(Bt, 1024, n0, 1024, Bs, k0);
        __syncthreads();
        mma128(As, Bs, acc);
        __syncthreads();
    }
    EPI_COORDS;
    #pragma unroll
    for (int i = 0; i < 4; ++i)
        #pragma unroll
        for (int j = 0; j < 4; ++j)
            #pragma unroll
            for (int r = 0; r < 4; ++r) {
                int m = m0 + wr + i * 16 + lrow4 + r;
                int n = n0 + wc + j * 16 + lcol;
                if (m >= M) continue;
                float v = acc[i][j][r];
                size_t o = (size_t)m * 1024 + n;
                if (MODE == 0) { ((ushort_t*)out0)[o] = f2bf(v + bias[n]); }
                else if (MODE == 1) {
                    v += bias[n];
                    ((ushort_t*)out0)[o] = f2bf(v + pbu[n]);
                    ((ushort_t*)out1)[o] = f2bf(v + pbv[n]);
                } else if (MODE == 2) { ((float*)out0)[o] = v + bias[n]; }
                else { ((ushort_t*)out0)[o] = f2bf(v); }
            }
}

// ---------------------------------------------------------------------------
// bdS[lb,h,t,s] = qv[b,t,h*128+:] . p[j,h*128+:], j = s + 1023 - t.
// Computed as dense GEMM over j; rel-shift applied in the store predicate:
// s = j + t - 1023, stored iff 0 <= s < 1024. Every (t,s) covered exactly once.
// grid (16, 8, nb*H)
// ---------------------------------------------------------------------------
__global__ __launch_bounds__(256)
void gemm_bd_shifted(const ushort_t* __restrict__ qv, const ushort_t* __restrict__ p,
                     ushort_t* __restrict__ bdS, int b0)
{
    __shared__ ushort_t As[128 * 64], Bs[128 * 64];
    const int j0 = blockIdx.x * 128, t0 = blockIdx.y * 128;
    const int lb = blockIdx.z >> 3, h = blockIdx.z & 7;
    const int b = b0 + lb;
    const ushort_t* Ab = qv + (size_t)b * T_ * D_ + h * DK_;
    const ushort_t* Bb = p + h * DK_;
    ACC_DECL;
    for (int k0 = 0; k0 < DK_; k0 += 64) {
        stage128x64(Ab, D_, t0, T_, As, k0);
        stage128x64(Bb, D_, j0, P_, Bs, k0);     // row 2047 clamped (never stored)
        __syncthreads();
        mma128(As, Bs, acc);
        __syncthreads();
    }
    EPI_COORDS;
    ushort_t* ob = bdS + (size_t)(lb * H_ + h) * T_ * T_;
    #pragma unroll
    for (int i = 0; i < 4; ++i)
        #pragma unroll
        for (int j = 0; j < 4; ++j)
            #pragma unroll
            for (int r = 0; r < 4; ++r) {
                int t = t0 + wr + i * 16 + lrow4 + r;
                int jj = j0 + wc + j * 16 + lcol;
                int s = jj + t - (T_ - 1);
                if (s >= 0 && s < T_)
                    ob[(size_t)t * T_ + s] = f2bf(acc[i][j][r]);
            }
}

// ---------------------------------------------------------------------------
// 512-thread swizzled stager: LDS [128][64] bf16 linear dest; global source
// pre-swizzled so that LDS slot (row, blk) holds global element (row, blk^(row&7)).
// ---------------------------------------------------------------------------
__device__ __forceinline__ void stage_swz(const ushort_t* __restrict__ g, int ldg,
                                          int rowBase, ushort_t* lds, int k0)
{
    const int tid = threadIdx.x;
    const int w = tid >> 6;
    #pragma unroll
    for (int u = 0; u < 2; ++u) {
        int e = tid * 8 + u * 4096;
        int row = e >> 6;
        int blk = (e >> 3) & 7;
        const ushort_t* src = g + (size_t)(rowBase + row) * ldg + k0 + ((blk ^ (row & 7)) << 3);
        ushort_t* dst = lds + w * 512 + u * 4096;
        gload_lds16(src, dst);
    }
}

// ---------------------------------------------------------------------------
// flash_attn: per block (t0, b, h): 512 thr = 8 waves (2 row-groups x 4 col-groups).
// Wave tile 64x32. For each s-tile (128):
//   acc_s = (mask ? NEG/SCALE : bdS) ; acc_s += qu.k (MFMA, k swizzle-staged)
//   online softmax (cross-wave stats via LDS), P -> Sp (bf16, swizzled)
//   acc_o = acc_o*rescale + P @ vT (MFMA, vT swizzle-staged)
// Epilogue: ctx = acc_o / l  (0 if row fully masked: m < -5000).
// grid (8, nb*H)
// ---------------------------------------------------------------------------
__global__ __launch_bounds__(512, 2)
void flash_attn(const ushort_t* __restrict__ qu, const ushort_t* __restrict__ kb,
                const ushort_t* __restrict__ vT, const ushort_t* __restrict__ bdS,
                const unsigned char* __restrict__ mask,
                ushort_t* __restrict__ ctx, int b0)
{
    __shared__ ushort_t Sb[128 * 64];
    __shared__ ushort_t Sp[2][128 * 64];
    __shared__ float stats_m[4][128];
    __shared__ float stats_l[4][128];

    const int tid = threadIdx.x;
    const int lane = tid & 63, w = tid >> 6;
    const int wr = (w >> 2) * 64, wc = (w & 3) * 32;
    const int wcol = w & 3;
    const int lr = lane & 15;          // frag row/col select
    const int lg = lane >> 4;          // k-group
    const int lrow4 = lg * 4;
    const int t0 = blockIdx.x * 128;
    const int lb = blockIdx.y >> 3, h = blockIdx.y & 7;
    const int b = b0 + lb;
    const int spHalf = wc >> 6;        // which Sp half this wave writes

    const ushort_t* quB = qu + (size_t)b * T_ * D_ + h * DK_;
    const ushort_t* kB  = kb + (size_t)b * T_ * D_ + h * DK_;
    const ushort_t* vTB = vT + (size_t)(b * H_ + h) * DK_ * T_;
    const ushort_t* bdB = bdS + (size_t)(lb * H_ + h) * T_ * T_;
    const unsigned char* mB = mask + (size_t)b * T_ * T_;

    f32x4 acc_o[4][2];
    float m_run[4][4], l_run[4][4];
    #pragma unroll
    for (int i = 0; i < 4; ++i) {
        #pragma unroll
        for (int j = 0; j < 2; ++j)
            #pragma unroll
            for (int r = 0; r < 4; ++r) acc_o[i][j][r] = 0.f;
        #pragma unroll
        for (int r = 0; r < 4; ++r) { m_run[i][r] = -3.0e38f; l_run[i][r] = 0.f; }
    }

    for (int s0 = 0; s0 < T_; s0 += 128) {
        // ---- acc_s init from bdS + mask (as MFMA C-operand) ----
        f32x4 acc_s[4][2];
        #pragma unroll
        for (int i = 0; i < 4; ++i)
            #pragma unroll
            for (int j = 0; j < 2; ++j)
                #pragma unroll
                for (int r = 0; r < 4; ++r) {
                    int t = t0 + wr + i * 16 + lrow4 + r;
                    int s = s0 + wc + j * 16 + lr;
                    size_t off = (size_t)t * T_ + s;
                    float bdv = bf2f(bdB[off]);
                    acc_s[i][j][r] = mB[off] ? (NEG_INF_F / SCALE_F) : bdv;
                }
        // ---- scores GEMM: acc_s += qu . k ----
        #pragma unroll
        for (int kh = 0; kh < 2; ++kh) {
            __syncthreads();                         // Sb free (prev readers done)
            stage_swz(kB, D_, s0, Sb, kh * 64);
            // qu fragments for this K-half (from global; L2-hot, transient regs)
            short8 aQ[2][4];
            #pragma unroll
            for (int kk = 0; kk < 2; ++kk)
                #pragma unroll
                for (int i = 0; i < 4; ++i)
                    aQ[kk][i] = *(const short8*)&quB[(size_t)(t0 + wr + i * 16 + lr) * D_
                                                     + kh * 64 + kk * 32 + lg * 8];
            __syncthreads();                         // staging complete
            #pragma unroll
            for (int kk = 0; kk < 2; ++kk) {
                short8 bf[2];
                #pragma unroll
                for (int j = 0; j < 2; ++j) {
                    int row = wc + j * 16 + lr;
                    bf[j] = *(const short8*)&Sb[row * 64 + (((kk * 4 + lg) ^ (row & 7)) << 3)];
                }
                #pragma unroll
                for (int i = 0; i < 4; ++i)
                    #pragma unroll
                    for (int j = 0; j < 2; ++j)
                        acc_s[i][j] = __builtin_amdgcn_mfma_f32_16x16x32_bf16(
                            aQ[kk][i], bf[j], acc_s[i][j], 0, 0, 0);
            }
        }
        // ---- online softmax ----
        float m_loc[4][4];
        #pragma unroll
        for (int i = 0; i < 4; ++i)
            #pragma unroll
            for (int r = 0; r < 4; ++r) {
                float mv = -3.0e38f;
                #pragma unroll
                for (int j = 0; j < 2; ++j) {
                    float sv = acc_s[i][j][r] * SCALE_F;
                    acc_s[i][j][r] = sv;
                    mv = fmaxf(mv, sv);
                }
                #pragma unroll
                for (int off = 1; off < 16; off <<= 1)
                    mv = fmaxf(mv, __shfl_xor(mv, off));
                m_loc[i][r] = mv;
            }
        if (lr == 0) {
            #pragma unroll
            for (int i = 0; i < 4; ++i)
                #pragma unroll
                for (int r = 0; r < 4; ++r)
                    stats_m[wcol][wr + i * 16 + lrow4 + r] = m_loc[i][r];
        }
        __syncthreads();
        float fsc[4][4];
        #pragma unroll
        for (int i = 0; i < 4; ++i)
            #pragma unroll
            for (int r = 0; r < 4; ++r) {
                int row = wr + i * 16 + lrow4 + r;
                float mt = fmaxf(fmaxf(stats_m[0][row], stats_m[1][row]),
                                 fmaxf(stats_m[2][row], stats_m[3][row]));
                float mn = fmaxf(m_run[i][r], mt);
                fsc[i][r] = __expf(m_run[i][r] - mn);
                m_run[i][r] = mn;
            }
        float ls[4][4];
        #pragma unroll
        for (int i = 0; i < 4; ++i)
            #pragma unroll
            for (int r = 0; r < 4; ++r) {
                float sum = 0.f;
                int row = wr + i * 16 + lrow4 + r;
                #pragma unroll
                for (int j = 0; j < 2; ++j) {
                    float pexp = __expf(acc_s[i][j][r] - m_run[i][r]);
                    sum += pexp;
                    int c = (wc & 63) + j * 16 + lr;
                    int slot = (((c >> 3) ^ (row & 7)) << 3) | (c & 7);
                    Sp[spHalf][row * 64 + slot] = f2bf(pexp);
                }
                #pragma unroll
                for (int off = 1; off < 16; off <<= 1)
                    sum += __shfl_xor(sum, off);
                ls[i][r] = sum;
            }
        if (lr == 0) {
            #pragma unroll
            for (int i = 0; i < 4; ++i)
                #pragma unroll
                for (int r = 0; r < 4; ++r)
                    stats_l[wcol][wr + i * 16 + lrow4 + r] = ls[i][r];
        }
        __syncthreads();                             // stats_l + Sp visible
        #pragma unroll
        for (int i = 0; i < 4; ++i)
            #pragma unroll
            for (int r = 0; r < 4; ++r) {
                int row = wr + i * 16 + lrow4 + r;
                float lt = stats_l[0][row] + stats_l[1][row]
                         + stats_l[2][row] + stats_l[3][row];
                l_run[i][r] = l_run[i][r] * fsc[i][r] + lt;
            }
        #pragma unroll
        for (int i = 0; i < 4; ++i)
            #pragma unroll
            for (int j = 0; j < 2; ++j)
                #pragma unroll
                for (int r = 0; r < 4; ++r)
                    acc_o[i][j][r] *= fsc[i][r];
        // ---- PV: acc_o += P @ vT ----
        #pragma unroll
        for (int sh = 0; sh < 2; ++sh) {
            if (sh) __syncthreads();                 // Sb free from sh=0 mma
            stage_swz(vTB, T_, 0, Sb, s0 + sh * 64);
            __syncthreads();
            #pragma unroll
            for (int kk = 0; kk < 2; ++kk) {
                short8 bf[2], af[4];
                #pragma unroll
                for (int j = 0; j < 2; ++j) {
                    int row = wc + j * 16 + lr;
                    bf[j] = *(const short8*)&Sb[row * 64 + (((kk * 4 + lg) ^ (row & 7)) << 3)];
                }
                #pragma unroll
                for (int i = 0; i < 4; ++i) {
                    int rowA = wr + i * 16 + lr;
                    af[i] = *(const short8*)&Sp[sh][rowA * 64 + (((kk * 4 + lg) ^ (rowA & 7)) << 3)];
                }
                #pragma unroll
                for (int i = 0; i < 4; ++i)
                    #pragma unroll
                    for (int j = 0; j < 2; ++j)
                        acc_o[i][j] = __builtin_amdgcn_mfma_f32_16x16x32_bf16(
                            af[i], bf[j], acc_o[i][j], 0, 0, 0);
            }
        }
    }
    // ---- epilogue: ctx = acc_o / l (0 if fully-masked row) ----
    #pragma unroll
    for (int i = 0; i < 4; ++i)
        #pragma unroll
        for (int r = 0; r < 4; ++r) {
            float inv = (m_run[i][r] < -5000.f) ? 0.f : 1.f / l_run[i][r];
            #pragma unroll
            for (int j = 0; j < 2; ++j) {
                int t = t0 + wr + i * 16 + lrow4 + r;
                int n = wc + j * 16 + lr;
                ctx[((size_t)(b * T_ + t)) * D_ + h * DK_ + n] = f2bf(acc_o[i][j][r] * inv);
            }
        }
}

// ---------------------------------------------------------------------------
// casts / transposes
// ---------------------------------------------------------------------------
__global__ __launch_bounds__(256)
void cast_bf16(const float* __restrict__ in, ushort_t* __restrict__ out, int n)
{
    int i = (blockIdx.x * 256 + threadIdx.x) * 8;
    if (i >= n) return;
    float4 a = *(const float4*)&in[i];
    float4 bq = *(const float4*)&in[i + 4];
    ushortx8 r;
    r[0] = f2bf(a.x); r[1] = f2bf(a.y); r[2] = f2bf(a.z); r[3] = f2bf(a.w);
    r[4] = f2bf(bq.x); r[5] = f2bf(bq.y); r[6] = f2bf(bq.z); r[7] = f2bf(bq.w);
    *(ushortx8*)&out[i] = r;
}

__global__ __launch_bounds__(256)
void wt_cast(const float* __restrict__ W, ushort_t* __restrict__ Wt)
{
    __shared__ float tile[32][33];
    const int n0 = blockIdx.x * 32, k0 = blockIdx.y * 32;
    const int lx = threadIdx.x & 31, ly = threadIdx.x >> 5;
    #pragma unroll
    for (int r = 0; r < 32; r += 8)
        tile[ly + r][lx] = W[(size_t)(k0 + ly + r) * 1024 + n0 + lx];
    __syncthreads();
    #pragma unroll
    for (int r = 0; r < 32; r += 8)
        Wt[(size_t)(n0 + ly + r) * 1024 + k0 + lx] = f2bf(tile[lx][ly + r]);
}

__global__ __launch_bounds__(256)
void vt_trans(const ushort_t* __restrict__ v, ushort_t* __restrict__ vT)
{
    __shared__ ushort_t tile[32][33];
    const int t0 = blockIdx.x * 32, n0 = blockIdx.y * 32;
    const int bh = blockIdx.z;
    const int b = bh >> 3, h = bh & 7;
    const int lx = threadIdx.x & 31, ly = threadIdx.x >> 5;
    const ushort_t* src = v + (size_t)b * T_ * D_ + h * DK_;
    #pragma unroll
    for (int r = 0; r < 32; r += 8)
        tile[ly + r][lx] = src[(size_t)(t0 + ly + r) * D_ + n0 + lx];
    __syncthreads();
    ushort_t* dst = vT + (size_t)bh * DK_ * T_;
    #pragma unroll
    for (int r = 0; r < 32; r += 8)
        dst[(size_t)(n0 + ly + r) * T_ + t0 + lx] = tile[lx][ly + r];
}

// ---------------------------------------------------------------------------
extern "C" void kernel_launch(void* const* d_in, const int* in_sizes, int n_in,
                              void* d_out, int out_size, void* d_ws, size_t ws_size,
                              hipStream_t stream)
{
    const float* query   = (const float*)d_in[0];
    const float* key     = (const float*)d_in[1];
    const float* value   = (const float*)d_in[2];
    const float* pos_emb = (const float*)d_in[3];
    const unsigned char* mask = (const unsigned char*)d_in[4];
    const float* Wq  = (const float*)d_in[5];
    const float* bq  = (const float*)d_in[6];
    const float* Wk  = (const float*)d_in[7];
    const float* bk  = (const float*)d_in[8];
    const float* Wv  = (const float*)d_in[9];
    const float* bv  = (const float*)d_in[10];
    const float* Wp  = (const float*)d_in[11];
    const float* Wo  = (const float*)d_in[12];
    const float* bo  = (const float*)d_in[13];
    const float* pbu = (const float*)d_in[14];
    const float* pbv = (const float*)d_in[15];
    float* out = (float*)d_out;

    const size_t SZ_BTD = (size_t)B_ * T_ * D_;       // 4,194,304
    const size_t SZ_PD  = (size_t)P_ * D_;            // 2,096,128
    const size_t SZ_W   = (size_t)D_ * D_;            // 1,048,576

    ushort_t* c = (ushort_t*)d_ws;
    ushort_t* qbf  = c; c += SZ_BTD;
    ushort_t* kbfi = c; c += SZ_BTD;
    ushort_t* vbfi = c; c += SZ_BTD;
    ushort_t* pbf  = c; c += SZ_PD;
    ushort_t* WqT = c; c += SZ_W;
    ushort_t* WkT = c; c += SZ_W;
    ushort_t* WvT = c; c += SZ_W;
    ushort_t* WpT = c; c += SZ_W;
    ushort_t* WoT = c; c += SZ_W;
    ushort_t* qu  = c; c += SZ_BTD;
    ushort_t* qv  = c; c += SZ_BTD;
    ushort_t* kb  = c; c += SZ_BTD;
    ushort_t* vb  = c; c += SZ_BTD;
    ushort_t* ctx = c; c += SZ_BTD;
    ushort_t* vT  = c; c += SZ_BTD;
    ushort_t* pp  = c; c += SZ_PD;

    const size_t base_bytes = (size_t)((char*)c - (char*)d_ws);
    const size_t per_b = (size_t)H_ * T_ * T_ * 2;    // bdS bf16 per batch
    int SB = 1;
    if (ws_size > base_bytes) {
        size_t sb = (ws_size - base_bytes) / per_b;
        SB = sb < 1 ? 1 : (sb > B_ ? B_ : (int)sb);
    }
    ushort_t* bdS = c;

    // casts
    cast_bf16<<<dim3((int)(SZ_BTD / 8 / 256)), 256, 0, stream>>>(query, qbf, (int)SZ_BTD);
    cast_bf16<<<dim3((int)(SZ_BTD / 8 / 256)), 256, 0, stream>>>(key, kbfi, (int)SZ_BTD);
    cast_bf16<<<dim3((int)(SZ_BTD / 8 / 256)), 256, 0, stream>>>(value, vbfi, (int)SZ_BTD);
    cast_bf16<<<dim3((int)((SZ_PD / 8 + 255) / 256)), 256, 0, stream>>>(pos_emb, pbf, (int)SZ_PD);
    wt_cast<<<dim3(32, 32), 256, 0, stream>>>(Wq, WqT);
    wt_cast<<<dim3(32, 32), 256, 0, stream>>>(Wk, WkT);
    wt_cast<<<dim3(32, 32), 256, 0, stream>>>(Wv, WvT);
    wt_cast<<<dim3(32, 32), 256, 0, stream>>>(Wp, WpT);
    wt_cast<<<dim3(32, 32), 256, 0, stream>>>(Wo, WoT);

    // projections
    gemm_proj_bt<1><<<dim3(8, 32), 256, 0, stream>>>(qbf, WqT, bq, qu, qv, pbu, pbv, B_ * T_);
    gemm_proj_bt<0><<<dim3(8, 32), 256, 0, stream>>>(kbfi, WkT, bk, kb, nullptr, nullptr, nullptr, B_ * T_);
    gemm_proj_bt<0><<<dim3(8, 32), 256, 0, stream>>>(vbfi, WvT, bv, vb, nullptr, nullptr, nullptr, B_ * T_);
    gemm_proj_bt<3><<<dim3(8, 16), 256, 0, stream>>>(pbf, WpT, nullptr, pp, nullptr, nullptr, nullptr, P_);
    vt_trans<<<dim3(32, 4, 32), 256, 0, stream>>>(vb, vT);

    // attention, chunked over batch
    for (int b0 = 0; b0 < B_; b0 += SB) {
        int nb = B_ - b0; if (nb > SB) nb = SB;
        gemm_bd_shifted<<<dim3(16, 8, nb * H_), 256, 0, stream>>>(qv, pp, bdS, b0);
        flash_attn     <<<dim3(8, nb * H_),     512, 0, stream>>>(qu, kb, vT, bdS, mask, ctx, b0);
    }

    // output projection (fp32 out)
    gemm_proj_bt<2><<<dim3(8, 32), 256, 0, stream>>>(ctx, WoT, bo, (void*)out, nullptr, nullptr, nullptr, B_ * T_);
}